// Round 4
// baseline (431.281 us; speedup 1.0000x reference)
//
#include <hip/hip_runtime.h>
#include <cstdint>
#include <cstddef>

// Problem constants (N=2, C=128, Ce=64, H=W=96)
#define HW_ 9216
#define CC 128
#define LOG2E 1.44269504088896f

typedef short bf16x8 __attribute__((ext_vector_type(8)));
typedef float f32x16 __attribute__((ext_vector_type(16)));
typedef float f32x4 __attribute__((ext_vector_type(4)));
typedef unsigned int u32x4 __attribute__((ext_vector_type(4)));

__device__ __forceinline__ unsigned short f2bf(float f) {
    unsigned int u = __builtin_bit_cast(unsigned int, f);
    u += 0x7FFFu + ((u >> 16) & 1u);   // RNE
    return (unsigned short)(u >> 16);
}

// ---------------------------------------------------------------------------
// Kernel 1: transpose weights into wt[c][o], o in [0,256)
// ---------------------------------------------------------------------------
__global__ __launch_bounds__(256) void prep_w(const float* __restrict__ w1,
                                              const float* __restrict__ w2,
                                              const float* __restrict__ wa,
                                              float* __restrict__ wt) {
    int idx = blockIdx.x * 256 + threadIdx.x;   // 32768 total
    int o = idx >> 7, c = idx & 127;
    float v;
    if (o < 64)       v = w1[o * 128 + c];
    else if (o < 128) v = w2[(o - 64) * 128 + c];
    else              v = wa[(o - 128) * 128 + c];
    wt[c * 256 + o] = v;
}

// ---------------------------------------------------------------------------
// Kernel 2: 1x1 conv + PReLU (fp32 accumulate), write bf16.
//   oset 0 -> Q[n][p][d] (pre-scaled by log2e), 1 -> K[n][p][d], 2,3 -> Vt[n][c][p]
// Weights via s_load (scalar pipe, parallel to the VALU fma stream).
// ---------------------------------------------------------------------------
__global__ __launch_bounds__(256) void conv_kernel(
    const float* __restrict__ x, const float* __restrict__ wt,
    const float* __restrict__ b1, const float* __restrict__ a1,
    const float* __restrict__ b2, const float* __restrict__ a2,
    const float* __restrict__ ba, const float* __restrict__ aa,
    unsigned short* __restrict__ qb, unsigned short* __restrict__ kb,
    unsigned short* __restrict__ vtb) {
    const int ptile = blockIdx.x;   // 144
    const int oset  = blockIdx.y;   // 4
    const int n     = blockIdx.z;   // 2
    const int t = threadIdx.x;
    const int p = t & 63;
    const int og = __builtin_amdgcn_readfirstlane(t >> 6);
    const int p0 = ptile * 64;

    __shared__ float xs[128 * 64];
    // vectorized x staging: 2048 float4, 8 per thread
#pragma unroll
    for (int kk = 0; kk < 8; kk++) {
        int f = t + kk * 256;
        int row = f >> 4, col4 = f & 15;
        *(f32x4*)&xs[row * 64 + col4 * 4] =
            *(const f32x4*)&x[((size_t)n * CC + row) * HW_ + p0 + col4 * 4];
    }
    __syncthreads();

    const int obase = oset * 64 + og * 16;
    float acc[16];
#pragma unroll
    for (int i = 0; i < 16; i++) acc[i] = 0.f;

#pragma unroll 4
    for (int c = 0; c < 128; c++) {
        float xv = xs[c * 64 + p];
        const float* wr = wt + c * 256 + obase;   // wave-uniform -> s_load
#pragma unroll
        for (int i = 0; i < 16; i++) acc[i] = fmaf(wr[i], xv, acc[i]);
    }

    const float* bias_p;
    const float* slope_p;
    if (oset == 0)      { bias_p = b1; slope_p = a1; }
    else if (oset == 1) { bias_p = b2; slope_p = a2; }
    else                { bias_p = ba; slope_p = aa; }
    const float slope = slope_p[0];

    unsigned short vals[16];
#pragma unroll
    for (int i = 0; i < 16; i++) {
        float bv = (oset < 2) ? bias_p[og * 16 + i] : bias_p[obase - 128 + i];
        float y = acc[i] + bv;
        y = (y >= 0.f) ? y : slope * y;
        if (oset == 0) y *= LOG2E;   // fold softmax ln->log2 into Q
        vals[i] = f2bf(y);
    }

    if (oset < 2) {
        unsigned short* dst = (oset == 0 ? qb : kb) + ((size_t)n * HW_ + p0 + p) * 64 + og * 16;
        bf16x8 v0, v1;
#pragma unroll
        for (int i = 0; i < 8; i++) { v0[i] = (short)vals[i]; v1[i] = (short)vals[8 + i]; }
        *(bf16x8*)(dst)     = v0;
        *(bf16x8*)(dst + 8) = v1;
    } else {
        int c0 = obase - 128;
#pragma unroll
        for (int i = 0; i < 16; i++)
            vtb[((size_t)n * CC + c0 + i) * HW_ + p0 + p] = vals[i];
    }
}

// ---------------------------------------------------------------------------
// Kernel 3: flash attention, S^T form, 32x32x16 MFMA, no-max softmax.
//   Block = 4 waves x 64 q = 256 q. j-tile 64/iter. Single 24 KB K+V LDS
//   buffer, VGPR cross-iteration prefetch (L2-friendly; round-2-proven).
//   P transpose C/D->B-operand done IN REGISTERS via shfl_xor(32) half-swaps
//   (no p_lds, no bank conflicts, no extra barrier).
//   Grid (nch, 72): chunk = blockIdx.x -> all 72 blocks of a chunk land on
//   one XCD (linear%8) -> K/V chunk (884 KB) L2-resident.
// ---------------------------------------------------------------------------
__global__ __launch_bounds__(256, 2) void attn_kernel(
    const unsigned short* __restrict__ qb, const unsigned short* __restrict__ kb,
    const unsigned short* __restrict__ vtb,
    float* __restrict__ o_part, float* __restrict__ l_part,
    int nch, int chunk_j) {
    const int chunk = blockIdx.x;          // nch
    const int n     = blockIdx.y / 36;     // 2
    const int qtb   = blockIdx.y % 36;     // 36
    const int t = threadIdx.x;
    const int w = t >> 6;
    const int lane = t & 63;
    const int l31 = lane & 31;
    const int h = lane >> 5;
    const int e7 = l31 & 7;

    __shared__ __align__(16) unsigned short k_lds[64 * 64];    // 8 KB  [j][d] swz
    __shared__ __align__(16) unsigned short v_lds[128 * 64];   // 16 KB [c][j] swz

    // Q B-frags: lane q = l31 (+qt*32 +w*64), d = dt*16 + h*8 + 0..7
    bf16x8 bq[2][4];
#pragma unroll
    for (int qt = 0; qt < 2; qt++) {
        const int row = qtb * 256 + w * 64 + qt * 32 + l31;
        const unsigned short* qp = qb + ((size_t)n * HW_ + row) * 64 + h * 8;
#pragma unroll
        for (int dt = 0; dt < 4; dt++)
            bq[qt][dt] = *(const bf16x8*)(qp + dt * 16);
    }

    f32x16 acc[4][2];
#pragma unroll
    for (int ct = 0; ct < 4; ct++)
#pragma unroll
        for (int qt = 0; qt < 2; qt++) acc[ct][qt] = (f32x16){};
    float l_s[2] = {0.f, 0.f};

    // staging index math: thread covers 2 K-rows and 4 V-rows (16B each)
    const int j0b = chunk * chunk_j;
    int krow[2], kseg[2], vrow[4], vseg[4];
#pragma unroll
    for (int i = 0; i < 2; i++) {
        int idx = (w * 2 + i) * 64 + lane;   // 0..511
        krow[i] = idx >> 3; kseg[i] = idx & 7;
    }
#pragma unroll
    for (int i = 0; i < 4; i++) {
        int idx = (w * 4 + i) * 64 + lane;   // 0..1023
        vrow[i] = idx >> 3; vseg[i] = idx & 7;
    }

    // prologue: load tile 0 into regs
    bf16x8 kr[2], vr[4];
#pragma unroll
    for (int i = 0; i < 2; i++)
        kr[i] = *(const bf16x8*)(kb + ((size_t)n * HW_ + j0b + krow[i]) * 64 + kseg[i] * 8);
#pragma unroll
    for (int i = 0; i < 4; i++)
        vr[i] = *(const bf16x8*)(vtb + ((size_t)n * CC + vrow[i]) * HW_ + j0b + vseg[i] * 8);

    const int iters = chunk_j / 64;
    for (int it = 0; it < iters; ++it) {
        __syncthreads();   // prior iteration's LDS reads complete
#pragma unroll
        for (int i = 0; i < 2; i++)
            *(bf16x8*)&k_lds[krow[i] * 64 + ((kseg[i] ^ (krow[i] & 7)) * 8)] = kr[i];
#pragma unroll
        for (int i = 0; i < 4; i++)
            *(bf16x8*)&v_lds[vrow[i] * 64 + ((vseg[i] ^ (vrow[i] & 7)) * 8)] = vr[i];
        __syncthreads();

        if (it + 1 < iters) {   // prefetch next tile; lands during compute
            const int j0n = j0b + (it + 1) * 64;
#pragma unroll
            for (int i = 0; i < 2; i++)
                kr[i] = *(const bf16x8*)(kb + ((size_t)n * HW_ + j0n + krow[i]) * 64 + kseg[i] * 8);
#pragma unroll
            for (int i = 0; i < 4; i++)
                vr[i] = *(const bf16x8*)(vtb + ((size_t)n * CC + vrow[i]) * HW_ + j0n + vseg[i] * 8);
        }

        // K A-frags: j = jt*32 + l31, d-chunk = dt*2 + h (swizzled)
        bf16x8 ak[2][4];
#pragma unroll
        for (int jt = 0; jt < 2; jt++)
#pragma unroll
            for (int dt = 0; dt < 4; dt++)
                ak[jt][dt] = *(const bf16x8*)&k_lds[(jt * 32 + l31) * 64 + (((dt * 2 + h) ^ e7) * 8)];

        // S^T, exp, sum, and in-register transpose to P^T B-frags
        bf16x8 bp[2][4];
#pragma unroll
        for (int qt = 0; qt < 2; qt++) {
            f32x16 s0 = (f32x16){}, s1 = (f32x16){};
#pragma unroll
            for (int dt = 0; dt < 4; dt++) {
                s0 = __builtin_amdgcn_mfma_f32_32x32x16_bf16(ak[0][dt], bq[qt][dt], s0, 0, 0, 0);
                s1 = __builtin_amdgcn_mfma_f32_32x32x16_bf16(ak[1][dt], bq[qt][dt], s1, 0, 0, 0);
            }
            float sum = 0.f;
#pragma unroll
            for (int r = 0; r < 16; r++) {
                float p0 = exp2f(s0[r]); s0[r] = p0; sum += p0;
                float p1 = exp2f(s1[r]); s1[r] = p1; sum += p1;
            }
            sum += __shfl_xor(sum, 32);
            l_s[qt] += sum;

            // transpose: C/D (row=(r&3)+8(r>>2)+4h) -> B-frag (k=h*8+i).
            // element i=4a+b of chunk jc comes from reg 4*(2(jc&1)+h)+b of
            // tile jc>>1, half h'=a  =>  pack reg-quads, swap halves via
            // shfl_xor(32), select by h.
#pragma unroll
            for (int jt = 0; jt < 2; jt++) {
                const f32x16& s = (jt == 0) ? s0 : s1;
                unsigned int G[4][2], X[4][2];
#pragma unroll
                for (int g = 0; g < 4; g++) {
                    G[g][0] = (unsigned int)f2bf(s[4 * g + 0]) | ((unsigned int)f2bf(s[4 * g + 1]) << 16);
                    G[g][1] = (unsigned int)f2bf(s[4 * g + 2]) | ((unsigned int)f2bf(s[4 * g + 3]) << 16);
                    X[g][0] = __shfl_xor((int)G[g][0], 32);
                    X[g][1] = __shfl_xor((int)G[g][1], 32);
                }
                u32x4 fe = h ? (u32x4){X[1][0], X[1][1], G[1][0], G[1][1]}
                             : (u32x4){G[0][0], G[0][1], X[0][0], X[0][1]};
                u32x4 fo = h ? (u32x4){X[3][0], X[3][1], G[3][0], G[3][1]}
                             : (u32x4){G[2][0], G[2][1], X[2][0], X[2][1]};
                bp[qt][2 * jt]     = __builtin_bit_cast(bf16x8, fe);
                bp[qt][2 * jt + 1] = __builtin_bit_cast(bf16x8, fo);
            }
        }

        // O^T += V^T P^T : A = V^T chunk (c-row, j-chunk jc), B = P^T
#pragma unroll
        for (int ct = 0; ct < 4; ct++) {
            bf16x8 av[4];
#pragma unroll
            for (int jc = 0; jc < 4; jc++)
                av[jc] = *(const bf16x8*)&v_lds[(ct * 32 + l31) * 64 + (((jc * 2 + h) ^ e7) * 8)];
#pragma unroll
            for (int qt = 0; qt < 2; qt++)
#pragma unroll
                for (int jc = 0; jc < 4; jc++)
                    acc[ct][qt] = __builtin_amdgcn_mfma_f32_32x32x16_bf16(av[jc], bp[qt][jc], acc[ct][qt], 0, 0, 0);
        }
    }

    // partials: O^T[c][q]; c = ct*32 + (r&3)+8*(r>>2)+4h, q col = l31
    const size_t obase = ((size_t)(chunk * 2 + n) * CC) * HW_;
#pragma unroll
    for (int ct = 0; ct < 4; ct++)
#pragma unroll
        for (int qt = 0; qt < 2; qt++) {
            const int p = qtb * 256 + w * 64 + qt * 32 + l31;
#pragma unroll
            for (int r = 0; r < 16; r++) {
                const int c = ct * 32 + (r & 3) + 8 * (r >> 2) + 4 * h;
                o_part[obase + (size_t)c * HW_ + p] = acc[ct][qt][r];
            }
        }
    if (h == 0) {
#pragma unroll
        for (int qt = 0; qt < 2; qt++)
            l_part[(size_t)(chunk * 2 + n) * HW_ + qtb * 256 + w * 64 + qt * 32 + l31] = l_s[qt];
    }
}

// ---------------------------------------------------------------------------
// Kernel 4: combine nch partials (plain sums - no max), write out[n][c][p].
// ---------------------------------------------------------------------------
__global__ __launch_bounds__(256) void combine_kernel(
    const float* __restrict__ o_part, const float* __restrict__ l_part,
    float* __restrict__ out, int nch) {
    int idx = blockIdx.x * 256 + threadIdx.x;   // < 2359296
    int p = idx % HW_;
    int nc = idx / HW_;          // n*128 + c
    int n = nc >> 7;
    float num = 0.f, den = 0.f;
    for (int ch = 0; ch < nch; ch++) {
        num += o_part[((size_t)(ch * 2 + n) * CC + (nc & 127)) * HW_ + p];
        den += l_part[(size_t)(ch * 2 + n) * HW_ + p];
    }
    out[idx] = num / den;
}

// ---------------------------------------------------------------------------
// Workspace layout (bytes):
//   wt 0 (131072) | qb 131072 (2359296) | kb 2490368 (2359296)
//   vtb 4849664 (4718592) | o_part 9568256 (nch*9437184) | l_part after
// nch=8 needs ~85.7 MB; fallback 4 (~47.6 MB) then 2 (~28.6 MB).
// ---------------------------------------------------------------------------
extern "C" void kernel_launch(void* const* d_in, const int* in_sizes, int n_in,
                              void* d_out, int out_size, void* d_ws, size_t ws_size,
                              hipStream_t stream) {
    const float* x  = (const float*)d_in[0];
    const float* w1 = (const float*)d_in[1];
    const float* b1 = (const float*)d_in[2];
    const float* a1 = (const float*)d_in[3];
    const float* w2 = (const float*)d_in[4];
    const float* b2 = (const float*)d_in[5];
    const float* a2 = (const float*)d_in[6];
    const float* wa = (const float*)d_in[7];
    const float* ba = (const float*)d_in[8];
    const float* aa = (const float*)d_in[9];
    float* out = (float*)d_out;

    auto need = [](int nc) -> size_t {
        return 9568256ull + (size_t)nc * 9437184ull + (size_t)nc * 2 * HW_ * 4;
    };
    int nch = 8;
    if (ws_size < need(8)) nch = 4;
    if (ws_size < need(4)) nch = 2;
    const int chunk_j = HW_ / nch;

    char* ws = (char*)d_ws;
    float*          wt     = (float*)(ws + 0);
    unsigned short* qb     = (unsigned short*)(ws + 131072);
    unsigned short* kb     = (unsigned short*)(ws + 2490368);
    unsigned short* vtb    = (unsigned short*)(ws + 4849664);
    float*          o_part = (float*)(ws + 9568256);
    float*          l_part = (float*)(ws + 9568256 + (size_t)nch * 9437184);

    hipLaunchKernelGGL(prep_w, dim3(128), dim3(256), 0, stream, w1, w2, wa, wt);
    hipLaunchKernelGGL(conv_kernel, dim3(144, 4, 2), dim3(256), 0, stream,
                       x, wt, b1, a1, b2, a2, ba, aa, qb, kb, vtb);
    hipLaunchKernelGGL(attn_kernel, dim3(nch, 72), dim3(256), 0, stream,
                       qb, kb, vtb, o_part, l_part, nch, chunk_j);
    hipLaunchKernelGGL(combine_kernel, dim3(2 * CC * HW_ / 256), dim3(256), 0, stream,
                       o_part, l_part, out, nch);
}

// Round 5
// 393.660 us; speedup vs baseline: 1.0956x; 1.0956x over previous
//
#include <hip/hip_runtime.h>
#include <cstdint>
#include <cstddef>

// Problem constants (N=2, C=128, Ce=64, H=W=96)
#define HW_ 9216
#define CC 128
#define NCH 6
#define CHUNKJ 1536   // HW_/NCH
#define ITERS 24      // CHUNKJ/64
#define LOG2E 1.44269504088896f

typedef short bf16x8 __attribute__((ext_vector_type(8)));
typedef float f32x16 __attribute__((ext_vector_type(16)));
typedef float f32x4 __attribute__((ext_vector_type(4)));
typedef unsigned int u32x4 __attribute__((ext_vector_type(4)));

__device__ __forceinline__ unsigned short f2bf(float f) {
    unsigned int u = __builtin_bit_cast(unsigned int, f);
    u += 0x7FFFu + ((u >> 16) & 1u);   // RNE
    return (unsigned short)(u >> 16);
}

// async 16B global->LDS DMA; HW dest = wave-uniform base + lane*16
__device__ __forceinline__ void cp16(const unsigned short* g, unsigned short* l) {
    __builtin_amdgcn_global_load_lds((__attribute__((address_space(1))) void*)g,
                                     (__attribute__((address_space(3))) void*)l,
                                     16, 0, 0);
}

// raw LDS read: opaque to the compiler's waitcnt pass (no auto vmcnt(0))
__device__ __forceinline__ u32x4 ds_read16(int byte_addr) {
    u32x4 r;
    asm volatile("ds_read_b128 %0, %1" : "=v"(r) : "v"(byte_addr));
    return r;
}
__device__ __forceinline__ void lgkm0_tie8(u32x4& a, u32x4& b, u32x4& c, u32x4& d,
                                           u32x4& e, u32x4& f, u32x4& g, u32x4& hh) {
    asm volatile("s_waitcnt lgkmcnt(0)"
                 : "+v"(a), "+v"(b), "+v"(c), "+v"(d),
                   "+v"(e), "+v"(f), "+v"(g), "+v"(hh) :: "memory");
}
__device__ __forceinline__ void lgkm0_tie4(u32x4& a, u32x4& b, u32x4& c, u32x4& d) {
    asm volatile("s_waitcnt lgkmcnt(0)"
                 : "+v"(a), "+v"(b), "+v"(c), "+v"(d) :: "memory");
}

// ---------------------------------------------------------------------------
// Kernel 1: transpose weights into wt[c][o], o in [0,256)
// ---------------------------------------------------------------------------
__global__ __launch_bounds__(256) void prep_w(const float* __restrict__ w1,
                                              const float* __restrict__ w2,
                                              const float* __restrict__ wa,
                                              float* __restrict__ wt) {
    int idx = blockIdx.x * 256 + threadIdx.x;   // 32768 total
    int o = idx >> 7, c = idx & 127;
    float v;
    if (o < 64)       v = w1[o * 128 + c];
    else if (o < 128) v = w2[(o - 64) * 128 + c];
    else              v = wa[(o - 128) * 128 + c];
    wt[c * 256 + o] = v;
}

// ---------------------------------------------------------------------------
// Kernel 2: 1x1 conv + PReLU (fp32 accumulate), write bf16.
//   oset 0 -> Q[n][p][d] (pre-scaled by log2e), 1 -> K[n][p][d], 2,3 -> Vt[n][c][p]
// ---------------------------------------------------------------------------
__global__ __launch_bounds__(256) void conv_kernel(
    const float* __restrict__ x, const float* __restrict__ wt,
    const float* __restrict__ b1, const float* __restrict__ a1,
    const float* __restrict__ b2, const float* __restrict__ a2,
    const float* __restrict__ ba, const float* __restrict__ aa,
    unsigned short* __restrict__ qb, unsigned short* __restrict__ kb,
    unsigned short* __restrict__ vtb) {
    const int ptile = blockIdx.x;   // 144
    const int oset  = blockIdx.y;   // 4
    const int n     = blockIdx.z;   // 2
    const int t = threadIdx.x;
    const int p = t & 63;
    const int og = __builtin_amdgcn_readfirstlane(t >> 6);
    const int p0 = ptile * 64;

    __shared__ float xs[128 * 64];
#pragma unroll
    for (int kk = 0; kk < 8; kk++) {
        int f = t + kk * 256;
        int row = f >> 4, col4 = f & 15;
        *(f32x4*)&xs[row * 64 + col4 * 4] =
            *(const f32x4*)&x[((size_t)n * CC + row) * HW_ + p0 + col4 * 4];
    }
    __syncthreads();

    const int obase = oset * 64 + og * 16;
    float acc[16];
#pragma unroll
    for (int i = 0; i < 16; i++) acc[i] = 0.f;

#pragma unroll 4
    for (int c = 0; c < 128; c++) {
        float xv = xs[c * 64 + p];
        const float* wr = wt + c * 256 + obase;   // wave-uniform -> s_load
#pragma unroll
        for (int i = 0; i < 16; i++) acc[i] = fmaf(wr[i], xv, acc[i]);
    }

    const float* bias_p;
    const float* slope_p;
    if (oset == 0)      { bias_p = b1; slope_p = a1; }
    else if (oset == 1) { bias_p = b2; slope_p = a2; }
    else                { bias_p = ba; slope_p = aa; }
    const float slope = slope_p[0];

    unsigned short vals[16];
#pragma unroll
    for (int i = 0; i < 16; i++) {
        float bv = (oset < 2) ? bias_p[og * 16 + i] : bias_p[obase - 128 + i];
        float y = acc[i] + bv;
        y = (y >= 0.f) ? y : slope * y;
        if (oset == 0) y *= LOG2E;   // fold softmax ln->log2 into Q
        vals[i] = f2bf(y);
    }

    if (oset < 2) {
        unsigned short* dst = (oset == 0 ? qb : kb) + ((size_t)n * HW_ + p0 + p) * 64 + og * 16;
        bf16x8 v0, v1;
#pragma unroll
        for (int i = 0; i < 8; i++) { v0[i] = (short)vals[i]; v1[i] = (short)vals[8 + i]; }
        *(bf16x8*)(dst)     = v0;
        *(bf16x8*)(dst + 8) = v1;
    } else {
        int c0 = obase - 128;
#pragma unroll
        for (int i = 0; i < 16; i++)
            vtb[((size_t)n * CC + c0 + i) * HW_ + p0 + p] = vals[i];
    }
}

// ---------------------------------------------------------------------------
// Kernel 3: flash attention, S^T form, 32x32x16 MFMA, no-max softmax.
//   q-tile 256 (4 waves x 64 q), nch=6, grid (36,6,2) -> 432 blocks <= 512
//   capacity (no herd tail).
//   Staging: 3-buffer global_load_lds pipeline, depth-2 prefetch, manual
//   `s_waitcnt vmcnt(6); s_barrier` (per-wave DMA count uniform = 6/tile).
//   K/V fragment reads via raw asm ds_read_b128 + register-tied lgkmcnt(0)
//   so the compiler inserts NO vmcnt in the K-loop (correctness is carried
//   entirely by the manual waits; cross-wave safety = wait-own-vmcnt BEFORE
//   the shared barrier).
// ---------------------------------------------------------------------------
__global__ __launch_bounds__(256, 2) void attn_kernel(
    const unsigned short* __restrict__ qb, const unsigned short* __restrict__ kb,
    const unsigned short* __restrict__ vtb,
    float* __restrict__ o_part, float* __restrict__ l_part) {
    const int qtb   = blockIdx.x;   // 36
    const int chunk = blockIdx.y;   // 6
    const int n     = blockIdx.z;   // 2
    const int t = threadIdx.x;
    const int w = t >> 6;
    const int lane = t & 63;
    const int l31 = lane & 31;
    const int h = lane >> 5;
    const int e7 = l31 & 7;

    // 3 buffers x (K 8 KB + V 16 KB) = 72 KB
    __shared__ __align__(16) unsigned short sbuf[3 * 12288];

    // Q B-frags: lane q = l31 (+qt*32 +w*64), d = dt*16 + h*8 + 0..7
    bf16x8 bq[2][4];
#pragma unroll
    for (int qt = 0; qt < 2; qt++) {
        const int row = qtb * 256 + w * 64 + qt * 32 + l31;
        const unsigned short* qp = qb + ((size_t)n * HW_ + row) * 64 + h * 8;
#pragma unroll
        for (int dt = 0; dt < 4; dt++)
            bq[qt][dt] = *(const bf16x8*)(qp + dt * 16);
    }
    // force Q completion here (before any DMA is issued) so the loop body
    // carries no compiler-visible vmem dependencies
    asm volatile("" : "+v"(bq[0][0]), "+v"(bq[0][1]), "+v"(bq[0][2]), "+v"(bq[0][3]),
                      "+v"(bq[1][0]), "+v"(bq[1][1]), "+v"(bq[1][2]), "+v"(bq[1][3]));

    f32x16 acc[4][2];
#pragma unroll
    for (int ct = 0; ct < 4; ct++)
#pragma unroll
        for (int qt = 0; qt < 2; qt++) acc[ct][qt] = (f32x16){};
    float l_s[2] = {0.f, 0.f};

    // DMA sources (swizzle folded into global source address).
    // K chunk kc = 2w+i covers LDS shorts [kc*512, +512): lane -> row kc*8+(lane>>3),
    // src seg = (lane&7)^(row&7). V chunk vc = 4w+i at 4096+vc*512, row = channel.
    const int j0b = chunk * CHUNKJ;
    const unsigned short* ks[2];
    const unsigned short* vs[4];
#pragma unroll
    for (int i = 0; i < 2; i++) {
        int kc = 2 * w + i;
        int row = kc * 8 + (lane >> 3);
        int seg = (lane & 7) ^ (row & 7);
        ks[i] = kb + ((size_t)n * HW_ + j0b + row) * 64 + seg * 8;
    }
#pragma unroll
    for (int i = 0; i < 4; i++) {
        int vc = 4 * w + i;
        int c = vc * 8 + (lane >> 3);
        int seg = (lane & 7) ^ (c & 7);
        vs[i] = vtb + ((size_t)n * CC + c) * HW_ + j0b + seg * 8;
    }

    // fragment-read byte offsets within a buffer
    int cho[4];
#pragma unroll
    for (int x = 0; x < 4; x++) cho[x] = ((x * 2 + h) ^ e7) * 16;
    const int jr0 = l31 * 128, jr1 = (32 + l31) * 128;

    // prologue: DMA tiles 0 and 1 into buffers 0,1 (12 per wave outstanding)
#pragma unroll
    for (int b = 0; b < 2; b++) {
        unsigned short* db = sbuf + b * 12288;
        cp16(ks[0] + b * 4096, db + (2 * w + 0) * 512);
        cp16(ks[1] + b * 4096, db + (2 * w + 1) * 512);
        cp16(vs[0] + b * 64, db + 4096 + (4 * w + 0) * 512);
        cp16(vs[1] + b * 64, db + 4096 + (4 * w + 1) * 512);
        cp16(vs[2] + b * 64, db + 4096 + (4 * w + 2) * 512);
        cp16(vs[3] + b * 64, db + 4096 + (4 * w + 3) * 512);
    }

    int cur = 0;
    for (int tI = 0; tI < ITERS; ++tI) {
        // my 6 DMAs for the current tile are done once <=6 remain outstanding;
        // barrier then guarantees ALL waves' DMAs for this buffer landed.
        asm volatile("s_waitcnt vmcnt(6)" ::: "memory");
        asm volatile("s_barrier" ::: "memory");

        {   // issue tile tI+2 into the buffer freed at this barrier
            int tt = tI + 2; if (tt >= ITERS) tt -= ITERS;   // wrap: harmless hot re-read
            int nb = cur + 2; if (nb >= 3) nb -= 3;
            unsigned short* db = sbuf + nb * 12288;
            cp16(ks[0] + tt * 4096, db + (2 * w + 0) * 512);
            cp16(ks[1] + tt * 4096, db + (2 * w + 1) * 512);
            cp16(vs[0] + tt * 64, db + 4096 + (4 * w + 0) * 512);
            cp16(vs[1] + tt * 64, db + 4096 + (4 * w + 1) * 512);
            cp16(vs[2] + tt * 64, db + 4096 + (4 * w + 2) * 512);
            cp16(vs[3] + tt * 64, db + 4096 + (4 * w + 3) * 512);
        }

        const int bufB = cur * 24576;

        // K A-frags: j = jt*32 + l31, d-chunk = dt*2 + h (swizzled)
        u32x4 akr[2][4];
#pragma unroll
        for (int dt = 0; dt < 4; dt++) akr[0][dt] = ds_read16(bufB + jr0 + cho[dt]);
#pragma unroll
        for (int dt = 0; dt < 4; dt++) akr[1][dt] = ds_read16(bufB + jr1 + cho[dt]);
        lgkm0_tie8(akr[0][0], akr[0][1], akr[0][2], akr[0][3],
                   akr[1][0], akr[1][1], akr[1][2], akr[1][3]);
        bf16x8 ak[2][4];
#pragma unroll
        for (int jt = 0; jt < 2; jt++)
#pragma unroll
            for (int dt = 0; dt < 4; dt++) ak[jt][dt] = __builtin_bit_cast(bf16x8, akr[jt][dt]);

        // S^T, exp, sum, in-register transpose to P^T B-frags
        bf16x8 bp[2][4];
#pragma unroll
        for (int qt = 0; qt < 2; qt++) {
            f32x16 s0 = (f32x16){}, s1 = (f32x16){};
#pragma unroll
            for (int dt = 0; dt < 4; dt++) {
                s0 = __builtin_amdgcn_mfma_f32_32x32x16_bf16(ak[0][dt], bq[qt][dt], s0, 0, 0, 0);
                s1 = __builtin_amdgcn_mfma_f32_32x32x16_bf16(ak[1][dt], bq[qt][dt], s1, 0, 0, 0);
            }
            float sum = 0.f;
#pragma unroll
            for (int r = 0; r < 16; r++) {
                float p0 = exp2f(s0[r]); s0[r] = p0; sum += p0;
                float p1 = exp2f(s1[r]); s1[r] = p1; sum += p1;
            }
            sum += __shfl_xor(sum, 32);
            l_s[qt] += sum;

            // C/D (row=(r&3)+8(r>>2)+4h) -> B-frag (k=h*8+i): pack reg-quads,
            // swap halves via shfl_xor(32), select by h. (round-4 verified)
#pragma unroll
            for (int jt = 0; jt < 2; jt++) {
                const f32x16& s = (jt == 0) ? s0 : s1;
                unsigned int G[4][2], X[4][2];
#pragma unroll
                for (int g = 0; g < 4; g++) {
                    G[g][0] = (unsigned int)f2bf(s[4 * g + 0]) | ((unsigned int)f2bf(s[4 * g + 1]) << 16);
                    G[g][1] = (unsigned int)f2bf(s[4 * g + 2]) | ((unsigned int)f2bf(s[4 * g + 3]) << 16);
                    X[g][0] = __shfl_xor((int)G[g][0], 32);
                    X[g][1] = __shfl_xor((int)G[g][1], 32);
                }
                u32x4 fe = h ? (u32x4){X[1][0], X[1][1], G[1][0], G[1][1]}
                             : (u32x4){G[0][0], G[0][1], X[0][0], X[0][1]};
                u32x4 fo = h ? (u32x4){X[3][0], X[3][1], G[3][0], G[3][1]}
                             : (u32x4){G[2][0], G[2][1], X[2][0], X[2][1]};
                bp[qt][2 * jt]     = __builtin_bit_cast(bf16x8, fe);
                bp[qt][2 * jt + 1] = __builtin_bit_cast(bf16x8, fo);
            }
        }

        // O^T += V^T P^T
#pragma unroll
        for (int ct = 0; ct < 4; ct++) {
            const int vrow = 8192 + (ct * 32 + l31) * 128;
            u32x4 avr[4];
#pragma unroll
            for (int jc = 0; jc < 4; jc++) avr[jc] = ds_read16(bufB + vrow + cho[jc]);
            lgkm0_tie4(avr[0], avr[1], avr[2], avr[3]);
#pragma unroll
            for (int qt = 0; qt < 2; qt++)
#pragma unroll
                for (int jc = 0; jc < 4; jc++)
                    acc[ct][qt] = __builtin_amdgcn_mfma_f32_32x32x16_bf16(
                        __builtin_bit_cast(bf16x8, avr[jc]), bp[qt][jc], acc[ct][qt], 0, 0, 0);
        }

        cur = (cur == 2) ? 0 : cur + 1;
    }
    asm volatile("s_waitcnt vmcnt(0)" ::: "memory");   // drain stray wrap DMAs

    // partials: O^T[c][q]; c = ct*32 + (r&3)+8*(r>>2)+4h, q col = l31
    const size_t obase = ((size_t)(chunk * 2 + n) * CC) * HW_;
#pragma unroll
    for (int ct = 0; ct < 4; ct++)
#pragma unroll
        for (int qt = 0; qt < 2; qt++) {
            const int p = qtb * 256 + w * 64 + qt * 32 + l31;
#pragma unroll
            for (int r = 0; r < 16; r++) {
                const int c = ct * 32 + (r & 3) + 8 * (r >> 2) + 4 * h;
                o_part[obase + (size_t)c * HW_ + p] = acc[ct][qt][r];
            }
        }
    if (h == 0) {
#pragma unroll
        for (int qt = 0; qt < 2; qt++)
            l_part[(size_t)(chunk * 2 + n) * HW_ + qtb * 256 + w * 64 + qt * 32 + l31] = l_s[qt];
    }
}

// ---------------------------------------------------------------------------
// Kernel 4: combine NCH partials (plain sums - no max), write out[n][c][p].
// ---------------------------------------------------------------------------
__global__ __launch_bounds__(256) void combine_kernel(
    const float* __restrict__ o_part, const float* __restrict__ l_part,
    float* __restrict__ out) {
    int idx = blockIdx.x * 256 + threadIdx.x;   // < 2359296
    int p = idx % HW_;
    int nc = idx / HW_;          // n*128 + c
    int n = nc >> 7;
    float num = 0.f, den = 0.f;
#pragma unroll
    for (int ch = 0; ch < NCH; ch++) {
        num += o_part[((size_t)(ch * 2 + n) * CC + (nc & 127)) * HW_ + p];
        den += l_part[(size_t)(ch * 2 + n) * HW_ + p];
    }
    out[idx] = num / den;
}

// ---------------------------------------------------------------------------
// Workspace layout (bytes), ~66.6 MB total:
//   wt 0 (131072) | qb 131072 (2359296) | kb 2490368 (2359296)
//   vtb 4849664 (4718592) | o_part 9568256 (6*9437184) | l_part after
// ---------------------------------------------------------------------------
extern "C" void kernel_launch(void* const* d_in, const int* in_sizes, int n_in,
                              void* d_out, int out_size, void* d_ws, size_t ws_size,
                              hipStream_t stream) {
    const float* x  = (const float*)d_in[0];
    const float* w1 = (const float*)d_in[1];
    const float* b1 = (const float*)d_in[2];
    const float* a1 = (const float*)d_in[3];
    const float* w2 = (const float*)d_in[4];
    const float* b2 = (const float*)d_in[5];
    const float* a2 = (const float*)d_in[6];
    const float* wa = (const float*)d_in[7];
    const float* ba = (const float*)d_in[8];
    const float* aa = (const float*)d_in[9];
    float* out = (float*)d_out;

    char* ws = (char*)d_ws;
    float*          wt     = (float*)(ws + 0);
    unsigned short* qb     = (unsigned short*)(ws + 131072);
    unsigned short* kb     = (unsigned short*)(ws + 2490368);
    unsigned short* vtb    = (unsigned short*)(ws + 4849664);
    float*          o_part = (float*)(ws + 9568256);
    float*          l_part = (float*)(ws + 9568256 + (size_t)NCH * 9437184);

    hipLaunchKernelGGL(prep_w, dim3(128), dim3(256), 0, stream, w1, w2, wa, wt);
    hipLaunchKernelGGL(conv_kernel, dim3(144, 4, 2), dim3(256), 0, stream,
                       x, wt, b1, a1, b2, a2, ba, aa, qb, kb, vtb);
    hipLaunchKernelGGL(attn_kernel, dim3(36, NCH, 2), dim3(256), 0, stream,
                       qb, kb, vtb, o_part, l_part);
    hipLaunchKernelGGL(combine_kernel, dim3(2 * CC * HW_ / 256), dim3(256), 0, stream,
                       o_part, l_part, out);
}

// Round 6
// 389.757 us; speedup vs baseline: 1.1065x; 1.0100x over previous
//
#include <hip/hip_runtime.h>
#include <cstdint>
#include <cstddef>

// Problem constants (N=2, C=128, Ce=64, H=W=96)
#define HW_ 9216
#define CC 128
#define NCH 6
#define CHUNKJ 1536   // HW_/NCH
#define ITERS 24      // CHUNKJ/64
#define NT_ 144       // HW_/64 j-tiles total
#define LOG2E 1.44269504088896f

typedef short bf16x8 __attribute__((ext_vector_type(8)));
typedef float f32x16 __attribute__((ext_vector_type(16)));
typedef float f32x4 __attribute__((ext_vector_type(4)));
typedef unsigned int u32x4 __attribute__((ext_vector_type(4)));

__device__ __forceinline__ unsigned short f2bf(float f) {
    unsigned int u = __builtin_bit_cast(unsigned int, f);
    u += 0x7FFFu + ((u >> 16) & 1u);   // RNE
    return (unsigned short)(u >> 16);
}

// async 16B global->LDS DMA; HW dest = wave-uniform base + lane*16
__device__ __forceinline__ void cp16(const unsigned short* g, unsigned short* l) {
    __builtin_amdgcn_global_load_lds((__attribute__((address_space(1))) void*)g,
                                     (__attribute__((address_space(3))) void*)l,
                                     16, 0, 0);
}

// raw LDS read: opaque to the compiler's waitcnt pass (no auto vmcnt(0))
__device__ __forceinline__ u32x4 ds_read16(int byte_addr) {
    u32x4 r;
    asm volatile("ds_read_b128 %0, %1" : "=v"(r) : "v"(byte_addr));
    return r;
}
__device__ __forceinline__ void lgkm0_tie8(u32x4& a, u32x4& b, u32x4& c, u32x4& d,
                                           u32x4& e, u32x4& f, u32x4& g, u32x4& hh) {
    asm volatile("s_waitcnt lgkmcnt(0)"
                 : "+v"(a), "+v"(b), "+v"(c), "+v"(d),
                   "+v"(e), "+v"(f), "+v"(g), "+v"(hh) :: "memory");
}
__device__ __forceinline__ void lgkm0_tie4(u32x4& a, u32x4& b, u32x4& c, u32x4& d) {
    asm volatile("s_waitcnt lgkmcnt(0)"
                 : "+v"(a), "+v"(b), "+v"(c), "+v"(d) :: "memory");
}

// ---------------------------------------------------------------------------
// Kernel 1: transpose weights into wt[c][o], o in [0,256)
// ---------------------------------------------------------------------------
__global__ __launch_bounds__(256) void prep_w(const float* __restrict__ w1,
                                              const float* __restrict__ w2,
                                              const float* __restrict__ wa,
                                              float* __restrict__ wt) {
    int idx = blockIdx.x * 256 + threadIdx.x;   // 32768 total
    int o = idx >> 7, c = idx & 127;
    float v;
    if (o < 64)       v = w1[o * 128 + c];
    else if (o < 128) v = w2[(o - 64) * 128 + c];
    else              v = wa[(o - 128) * 128 + c];
    wt[c * 256 + o] = v;
}

// ---------------------------------------------------------------------------
// Kernel 2: 1x1 conv + PReLU (fp32 accumulate), write bf16.
//   oset 0 -> Q[n][p][d] (pre-scaled by log2e), 1 -> K[n][p][d]
//   oset 2,3 -> Vt TILED: vtb[n][jt][c][64]  (16 KB contiguous per j-tile ->
//   sequential DRAM reads in the attention DMA; r5's [c][p] layout caused
//   128B-at-18KB-stride gathers = the 2.1 TB/s cap)
// ---------------------------------------------------------------------------
__global__ __launch_bounds__(256) void conv_kernel(
    const float* __restrict__ x, const float* __restrict__ wt,
    const float* __restrict__ b1, const float* __restrict__ a1,
    const float* __restrict__ b2, const float* __restrict__ a2,
    const float* __restrict__ ba, const float* __restrict__ aa,
    unsigned short* __restrict__ qb, unsigned short* __restrict__ kb,
    unsigned short* __restrict__ vtb) {
    const int ptile = blockIdx.x;   // 144
    const int oset  = blockIdx.y;   // 4
    const int n     = blockIdx.z;   // 2
    const int t = threadIdx.x;
    const int p = t & 63;
    const int og = __builtin_amdgcn_readfirstlane(t >> 6);
    const int p0 = ptile * 64;

    __shared__ float xs[128 * 64];
#pragma unroll
    for (int kk = 0; kk < 8; kk++) {
        int f = t + kk * 256;
        int row = f >> 4, col4 = f & 15;
        *(f32x4*)&xs[row * 64 + col4 * 4] =
            *(const f32x4*)&x[((size_t)n * CC + row) * HW_ + p0 + col4 * 4];
    }
    __syncthreads();

    const int obase = oset * 64 + og * 16;
    float acc[16];
#pragma unroll
    for (int i = 0; i < 16; i++) acc[i] = 0.f;

#pragma unroll 4
    for (int c = 0; c < 128; c++) {
        float xv = xs[c * 64 + p];
        const float* wr = wt + c * 256 + obase;   // wave-uniform -> s_load
#pragma unroll
        for (int i = 0; i < 16; i++) acc[i] = fmaf(wr[i], xv, acc[i]);
    }

    const float* bias_p;
    const float* slope_p;
    if (oset == 0)      { bias_p = b1; slope_p = a1; }
    else if (oset == 1) { bias_p = b2; slope_p = a2; }
    else                { bias_p = ba; slope_p = aa; }
    const float slope = slope_p[0];

    unsigned short vals[16];
#pragma unroll
    for (int i = 0; i < 16; i++) {
        float bv = (oset < 2) ? bias_p[og * 16 + i] : bias_p[obase - 128 + i];
        float y = acc[i] + bv;
        y = (y >= 0.f) ? y : slope * y;
        if (oset == 0) y *= LOG2E;   // fold softmax ln->log2 into Q
        vals[i] = f2bf(y);
    }

    if (oset < 2) {
        unsigned short* dst = (oset == 0 ? qb : kb) + ((size_t)n * HW_ + p0 + p) * 64 + og * 16;
        bf16x8 v0, v1;
#pragma unroll
        for (int i = 0; i < 8; i++) { v0[i] = (short)vals[i]; v1[i] = (short)vals[8 + i]; }
        *(bf16x8*)(dst)     = v0;
        *(bf16x8*)(dst + 8) = v1;
    } else {
        int c0 = obase - 128;
        unsigned short* vdst = vtb + (((size_t)n * NT_ + ptile) * CC) * 64;
#pragma unroll
        for (int i = 0; i < 16; i++)
            vdst[(c0 + i) * 64 + p] = vals[i];
    }
}

// ---------------------------------------------------------------------------
// Kernel 3: flash attention, S^T form, 32x32x16 MFMA, no-max softmax.
//   q-tile 256 (4 waves x 64 q), nch=6, grid (36,6,2) = 432 blocks <= 512.
//   3-buffer global_load_lds pipeline, depth-2 prefetch, manual
//   `s_waitcnt vmcnt(6); s_barrier`; raw ds_read_b128 + tied lgkmcnt(0)
//   (no compiler vmcnt in the K-loop). All sources tile-contiguous now:
//   K tile = 8 KB seq, V tile = 16 KB seq.
// ---------------------------------------------------------------------------
__global__ __launch_bounds__(256, 2) void attn_kernel(
    const unsigned short* __restrict__ qb, const unsigned short* __restrict__ kb,
    const unsigned short* __restrict__ vtb,
    float* __restrict__ o_part, float* __restrict__ l_part) {
    const int qtb   = blockIdx.x;   // 36
    const int chunk = blockIdx.y;   // 6
    const int n     = blockIdx.z;   // 2
    const int t = threadIdx.x;
    const int w = t >> 6;
    const int lane = t & 63;
    const int l31 = lane & 31;
    const int h = lane >> 5;
    const int e7 = l31 & 7;

    // 3 buffers x (K 8 KB + V 16 KB) = 72 KB
    __shared__ __align__(16) unsigned short sbuf[3 * 12288];

    // Q B-frags: lane q = l31 (+qt*32 +w*64), d = dt*16 + h*8 + 0..7
    bf16x8 bq[2][4];
#pragma unroll
    for (int qt = 0; qt < 2; qt++) {
        const int row = qtb * 256 + w * 64 + qt * 32 + l31;
        const unsigned short* qp = qb + ((size_t)n * HW_ + row) * 64 + h * 8;
#pragma unroll
        for (int dt = 0; dt < 4; dt++)
            bq[qt][dt] = *(const bf16x8*)(qp + dt * 16);
    }
    // force Q completion before any DMA so the loop has no compiler-visible
    // vmem dependencies
    asm volatile("" : "+v"(bq[0][0]), "+v"(bq[0][1]), "+v"(bq[0][2]), "+v"(bq[0][3]),
                      "+v"(bq[1][0]), "+v"(bq[1][1]), "+v"(bq[1][2]), "+v"(bq[1][3]));

    f32x16 acc[4][2];
#pragma unroll
    for (int ct = 0; ct < 4; ct++)
#pragma unroll
        for (int qt = 0; qt < 2; qt++) acc[ct][qt] = (f32x16){};
    float l_s[2] = {0.f, 0.f};

    // DMA sources (swizzle folded into source address; dest = base+lane*16).
    // K chunk kc=2w+i -> LDS shorts [kc*512,+512): row kc*8+(lane>>3),
    //   seg (lane&7)^(row&7); source advances 4096 shorts (8 KB) per tile.
    // V chunk vc=4w+i at 4096+vc*512: c = vc*8+(lane>>3), jl-chunk
    //   (lane&7)^(c&7); tiled source advances 8192 shorts (16 KB) per tile.
    const int j0b = chunk * CHUNKJ;
    const int t0 = chunk * ITERS;   // first tile index of this chunk
    const unsigned short* ks[2];
    const unsigned short* vs[4];
#pragma unroll
    for (int i = 0; i < 2; i++) {
        int kc = 2 * w + i;
        int row = kc * 8 + (lane >> 3);
        int seg = (lane & 7) ^ (row & 7);
        ks[i] = kb + ((size_t)n * HW_ + j0b + row) * 64 + seg * 8;
    }
#pragma unroll
    for (int i = 0; i < 4; i++) {
        int vc = 4 * w + i;
        int c = vc * 8 + (lane >> 3);
        int seg = (lane & 7) ^ (c & 7);
        vs[i] = vtb + (((size_t)n * NT_ + t0) * CC + c) * 64 + seg * 8;
    }

    // fragment-read byte offsets within a buffer
    int cho[4];
#pragma unroll
    for (int x = 0; x < 4; x++) cho[x] = ((x * 2 + h) ^ e7) * 16;
    const int jr0 = l31 * 128, jr1 = (32 + l31) * 128;

    // prologue: DMA tiles 0 and 1 into buffers 0,1 (12/wave outstanding)
#pragma unroll
    for (int b = 0; b < 2; b++) {
        unsigned short* db = sbuf + b * 12288;
        cp16(ks[0] + b * 4096, db + (2 * w + 0) * 512);
        cp16(ks[1] + b * 4096, db + (2 * w + 1) * 512);
        cp16(vs[0] + b * 8192, db + 4096 + (4 * w + 0) * 512);
        cp16(vs[1] + b * 8192, db + 4096 + (4 * w + 1) * 512);
        cp16(vs[2] + b * 8192, db + 4096 + (4 * w + 2) * 512);
        cp16(vs[3] + b * 8192, db + 4096 + (4 * w + 3) * 512);
    }

    int cur = 0;
    for (int tI = 0; tI < ITERS; ++tI) {
        // my 6 DMAs for the current tile done once <=6 remain outstanding;
        // barrier then guarantees ALL waves' DMAs for this buffer landed.
        asm volatile("s_waitcnt vmcnt(6)" ::: "memory");
        asm volatile("s_barrier" ::: "memory");

        {   // issue tile tI+2 into the buffer freed at this barrier
            int tt = tI + 2; if (tt >= ITERS) tt -= ITERS;   // wrap: hot re-read
            int nb = cur + 2; if (nb >= 3) nb -= 3;
            unsigned short* db = sbuf + nb * 12288;
            cp16(ks[0] + tt * 4096, db + (2 * w + 0) * 512);
            cp16(ks[1] + tt * 4096, db + (2 * w + 1) * 512);
            cp16(vs[0] + tt * 8192, db + 4096 + (4 * w + 0) * 512);
            cp16(vs[1] + tt * 8192, db + 4096 + (4 * w + 1) * 512);
            cp16(vs[2] + tt * 8192, db + 4096 + (4 * w + 2) * 512);
            cp16(vs[3] + tt * 8192, db + 4096 + (4 * w + 3) * 512);
        }

        const int bufB = cur * 24576;

        // K A-frags: j = jt*32 + l31, d-chunk = dt*2 + h (swizzled)
        u32x4 akr[2][4];
#pragma unroll
        for (int dt = 0; dt < 4; dt++) akr[0][dt] = ds_read16(bufB + jr0 + cho[dt]);
#pragma unroll
        for (int dt = 0; dt < 4; dt++) akr[1][dt] = ds_read16(bufB + jr1 + cho[dt]);
        lgkm0_tie8(akr[0][0], akr[0][1], akr[0][2], akr[0][3],
                   akr[1][0], akr[1][1], akr[1][2], akr[1][3]);
        bf16x8 ak[2][4];
#pragma unroll
        for (int jt = 0; jt < 2; jt++)
#pragma unroll
            for (int dt = 0; dt < 4; dt++) ak[jt][dt] = __builtin_bit_cast(bf16x8, akr[jt][dt]);

        // S^T, exp, sum, in-register transpose to P^T B-frags
        bf16x8 bp[2][4];
#pragma unroll
        for (int qt = 0; qt < 2; qt++) {
            f32x16 s0 = (f32x16){}, s1 = (f32x16){};
#pragma unroll
            for (int dt = 0; dt < 4; dt++) {
                s0 = __builtin_amdgcn_mfma_f32_32x32x16_bf16(ak[0][dt], bq[qt][dt], s0, 0, 0, 0);
                s1 = __builtin_amdgcn_mfma_f32_32x32x16_bf16(ak[1][dt], bq[qt][dt], s1, 0, 0, 0);
            }
            float sum = 0.f;
#pragma unroll
            for (int r = 0; r < 16; r++) {
                float p0 = exp2f(s0[r]); s0[r] = p0; sum += p0;
                float p1 = exp2f(s1[r]); s1[r] = p1; sum += p1;
            }
            sum += __shfl_xor(sum, 32);
            l_s[qt] += sum;

            // C/D (row=(r&3)+8(r>>2)+4h) -> B-frag (k=h*8+i): pack reg-quads,
            // swap halves via shfl_xor(32), select by h. (round-4 verified)
#pragma unroll
            for (int jt = 0; jt < 2; jt++) {
                const f32x16& s = (jt == 0) ? s0 : s1;
                unsigned int G[4][2], X[4][2];
#pragma unroll
                for (int g = 0; g < 4; g++) {
                    G[g][0] = (unsigned int)f2bf(s[4 * g + 0]) | ((unsigned int)f2bf(s[4 * g + 1]) << 16);
                    G[g][1] = (unsigned int)f2bf(s[4 * g + 2]) | ((unsigned int)f2bf(s[4 * g + 3]) << 16);
                    X[g][0] = __shfl_xor((int)G[g][0], 32);
                    X[g][1] = __shfl_xor((int)G[g][1], 32);
                }
                u32x4 fe = h ? (u32x4){X[1][0], X[1][1], G[1][0], G[1][1]}
                             : (u32x4){G[0][0], G[0][1], X[0][0], X[0][1]};
                u32x4 fo = h ? (u32x4){X[3][0], X[3][1], G[3][0], G[3][1]}
                             : (u32x4){G[2][0], G[2][1], X[2][0], X[2][1]};
                bp[qt][2 * jt]     = __builtin_bit_cast(bf16x8, fe);
                bp[qt][2 * jt + 1] = __builtin_bit_cast(bf16x8, fo);
            }
        }

        // O^T += V^T P^T
#pragma unroll
        for (int ct = 0; ct < 4; ct++) {
            const int vrow = 8192 + (ct * 32 + l31) * 128;
            u32x4 avr[4];
#pragma unroll
            for (int jc = 0; jc < 4; jc++) avr[jc] = ds_read16(bufB + vrow + cho[jc]);
            lgkm0_tie4(avr[0], avr[1], avr[2], avr[3]);
#pragma unroll
            for (int qt = 0; qt < 2; qt++)
#pragma unroll
                for (int jc = 0; jc < 4; jc++)
                    acc[ct][qt] = __builtin_amdgcn_mfma_f32_32x32x16_bf16(
                        __builtin_bit_cast(bf16x8, avr[jc]), bp[qt][jc], acc[ct][qt], 0, 0, 0);
        }

        cur = (cur == 2) ? 0 : cur + 1;
    }
    asm volatile("s_waitcnt vmcnt(0)" ::: "memory");   // drain wrap DMAs

    // partials: O^T[c][q]; c = ct*32 + (r&3)+8*(r>>2)+4h, q col = l31
    const size_t obase = ((size_t)(chunk * 2 + n) * CC) * HW_;
#pragma unroll
    for (int ct = 0; ct < 4; ct++)
#pragma unroll
        for (int qt = 0; qt < 2; qt++) {
            const int p = qtb * 256 + w * 64 + qt * 32 + l31;
#pragma unroll
            for (int r = 0; r < 16; r++) {
                const int c = ct * 32 + (r & 3) + 8 * (r >> 2) + 4 * h;
                o_part[obase + (size_t)c * HW_ + p] = acc[ct][qt][r];
            }
        }
    if (h == 0) {
#pragma unroll
        for (int qt = 0; qt < 2; qt++)
            l_part[(size_t)(chunk * 2 + n) * HW_ + qtb * 256 + w * 64 + qt * 32 + l31] = l_s[qt];
    }
}

// ---------------------------------------------------------------------------
// Kernel 4: combine NCH partials (plain sums - no max), write out[n][c][p].
// ---------------------------------------------------------------------------
__global__ __launch_bounds__(256) void combine_kernel(
    const float* __restrict__ o_part, const float* __restrict__ l_part,
    float* __restrict__ out) {
    int idx = blockIdx.x * 256 + threadIdx.x;   // < 2359296
    int p = idx % HW_;
    int nc = idx / HW_;          // n*128 + c
    int n = nc >> 7;
    float num = 0.f, den = 0.f;
#pragma unroll
    for (int ch = 0; ch < NCH; ch++) {
        num += o_part[((size_t)(ch * 2 + n) * CC + (nc & 127)) * HW_ + p];
        den += l_part[(size_t)(ch * 2 + n) * HW_ + p];
    }
    out[idx] = num / den;
}

// ---------------------------------------------------------------------------
// Workspace layout (bytes), ~66.6 MB total:
//   wt 0 (131072) | qb 131072 (2359296) | kb 2490368 (2359296)
//   vtb 4849664 (4718592, tiled [n][jt][c][64]) | o_part 9568256 (6*9437184)
//   | l_part after
// ---------------------------------------------------------------------------
extern "C" void kernel_launch(void* const* d_in, const int* in_sizes, int n_in,
                              void* d_out, int out_size, void* d_ws, size_t ws_size,
                              hipStream_t stream) {
    const float* x  = (const float*)d_in[0];
    const float* w1 = (const float*)d_in[1];
    const float* b1 = (const float*)d_in[2];
    const float* a1 = (const float*)d_in[3];
    const float* w2 = (const float*)d_in[4];
    const float* b2 = (const float*)d_in[5];
    const float* a2 = (const float*)d_in[6];
    const float* wa = (const float*)d_in[7];
    const float* ba = (const float*)d_in[8];
    const float* aa = (const float*)d_in[9];
    float* out = (float*)d_out;

    char* ws = (char*)d_ws;
    float*          wt     = (float*)(ws + 0);
    unsigned short* qb     = (unsigned short*)(ws + 131072);
    unsigned short* kb     = (unsigned short*)(ws + 2490368);
    unsigned short* vtb    = (unsigned short*)(ws + 4849664);
    float*          o_part = (float*)(ws + 9568256);
    float*          l_part = (float*)(ws + 9568256 + (size_t)NCH * 9437184);

    hipLaunchKernelGGL(prep_w, dim3(128), dim3(256), 0, stream, w1, w2, wa, wt);
    hipLaunchKernelGGL(conv_kernel, dim3(144, 4, 2), dim3(256), 0, stream,
                       x, wt, b1, a1, b2, a2, ba, aa, qb, kb, vtb);
    hipLaunchKernelGGL(attn_kernel, dim3(36, NCH, 2), dim3(256), 0, stream,
                       qb, kb, vtb, o_part, l_part);
    hipLaunchKernelGGL(combine_kernel, dim3(2 * CC * HW_ / 256), dim3(256), 0, stream,
                       o_part, l_part, out);
}

// Round 7
// 281.185 us; speedup vs baseline: 1.5338x; 1.3861x over previous
//
#include <hip/hip_runtime.h>
#include <cstdint>
#include <cstddef>

// Problem constants (N=2, C=128, Ce=64, H=W=96)
#define HW_ 9216
#define CC 128
#define NCH 6
#define CHUNKJ 1536   // HW_/NCH
#define ITERS 24      // CHUNKJ/64
#define NT_ 144       // HW_/64 j-tiles total
#define LOG2E 1.44269504088896f
#define CTR_OFF 66633728ull   // ws offset of sync counters

typedef short bf16x8 __attribute__((ext_vector_type(8)));
typedef float f32x16 __attribute__((ext_vector_type(16)));
typedef float f32x4 __attribute__((ext_vector_type(4)));
typedef unsigned int u32x4 __attribute__((ext_vector_type(4)));

__device__ __forceinline__ unsigned short f2bf(float f) {
    unsigned int u = __builtin_bit_cast(unsigned int, f);
    u += 0x7FFFu + ((u >> 16) & 1u);   // RNE
    return (unsigned short)(u >> 16);
}

// async 16B global->LDS DMA; HW dest = wave-uniform base + lane*16
__device__ __forceinline__ void cp16(const unsigned short* g, unsigned short* l) {
    __builtin_amdgcn_global_load_lds((__attribute__((address_space(1))) void*)g,
                                     (__attribute__((address_space(3))) void*)l,
                                     16, 0, 0);
}

// raw LDS read: opaque to the compiler's waitcnt pass (no auto vmcnt(0))
__device__ __forceinline__ u32x4 ds_read16(int byte_addr) {
    u32x4 r;
    asm volatile("ds_read_b128 %0, %1" : "=v"(r) : "v"(byte_addr));
    return r;
}
__device__ __forceinline__ void lgkm0_tie8(u32x4& a, u32x4& b, u32x4& c, u32x4& d,
                                           u32x4& e, u32x4& f, u32x4& g, u32x4& hh) {
    asm volatile("s_waitcnt lgkmcnt(0)"
                 : "+v"(a), "+v"(b), "+v"(c), "+v"(d),
                   "+v"(e), "+v"(f), "+v"(g), "+v"(hh) :: "memory");
}
__device__ __forceinline__ void lgkm0_tie4(u32x4& a, u32x4& b, u32x4& c, u32x4& d) {
    asm volatile("s_waitcnt lgkmcnt(0)"
                 : "+v"(a), "+v"(b), "+v"(c), "+v"(d) :: "memory");
}

// ---------------------------------------------------------------------------
// Kernel 1: transpose weights into wt[c][o], o in [0,256)
// ---------------------------------------------------------------------------
__global__ __launch_bounds__(256) void prep_w(const float* __restrict__ w1,
                                              const float* __restrict__ w2,
                                              const float* __restrict__ wa,
                                              float* __restrict__ wt) {
    int idx = blockIdx.x * 256 + threadIdx.x;   // 32768 total
    int o = idx >> 7, c = idx & 127;
    float v;
    if (o < 64)       v = w1[o * 128 + c];
    else if (o < 128) v = w2[(o - 64) * 128 + c];
    else              v = wa[(o - 128) * 128 + c];
    wt[c * 256 + o] = v;
}

// ---------------------------------------------------------------------------
// Kernel 2: 1x1 conv + PReLU (fp32 accumulate), write bf16.
//   oset 0 -> Q[n][p][d] plain (pre-scaled by log2e)
//   oset 1 -> K PRE-SWIZZLED: kb[(n*HW+j)*64 + (s^(j&7))*8 + e] = K[j][s*8+e]
//   oset 2,3 -> V PRE-SWIZZLED+TILED:
//     vtb[((n*NT+jt)*128+c)*64 + (sp^(c&7))*8 + ep] = V[c][jt*64 + sp*8+ep]
//   -> attention DMA sources become perfectly linear (base + lane*16), and the
//   LDS image (incl. bank swizzle) is byte-identical to rounds 4-6.
// ---------------------------------------------------------------------------
__global__ __launch_bounds__(256) void conv_kernel(
    const float* __restrict__ x, const float* __restrict__ wt,
    const float* __restrict__ b1, const float* __restrict__ a1,
    const float* __restrict__ b2, const float* __restrict__ a2,
    const float* __restrict__ ba, const float* __restrict__ aa,
    unsigned short* __restrict__ qb, unsigned short* __restrict__ kb,
    unsigned short* __restrict__ vtb) {
    const int ptile = blockIdx.x;   // 144
    const int oset  = blockIdx.y;   // 4
    const int n     = blockIdx.z;   // 2
    const int t = threadIdx.x;
    const int p = t & 63;
    const int og = __builtin_amdgcn_readfirstlane(t >> 6);
    const int p0 = ptile * 64;

    __shared__ float xs[128 * 64];
#pragma unroll
    for (int kk = 0; kk < 8; kk++) {
        int f = t + kk * 256;
        int row = f >> 4, col4 = f & 15;
        *(f32x4*)&xs[row * 64 + col4 * 4] =
            *(const f32x4*)&x[((size_t)n * CC + row) * HW_ + p0 + col4 * 4];
    }
    __syncthreads();

    const int obase = oset * 64 + og * 16;
    float acc[16];
#pragma unroll
    for (int i = 0; i < 16; i++) acc[i] = 0.f;

#pragma unroll 4
    for (int c = 0; c < 128; c++) {
        float xv = xs[c * 64 + p];
        const float* wr = wt + c * 256 + obase;   // wave-uniform -> s_load
#pragma unroll
        for (int i = 0; i < 16; i++) acc[i] = fmaf(wr[i], xv, acc[i]);
    }

    const float* bias_p;
    const float* slope_p;
    if (oset == 0)      { bias_p = b1; slope_p = a1; }
    else if (oset == 1) { bias_p = b2; slope_p = a2; }
    else                { bias_p = ba; slope_p = aa; }
    const float slope = slope_p[0];

    unsigned short vals[16];
#pragma unroll
    for (int i = 0; i < 16; i++) {
        float bv = (oset < 2) ? bias_p[og * 16 + i] : bias_p[obase - 128 + i];
        float y = acc[i] + bv;
        y = (y >= 0.f) ? y : slope * y;
        if (oset == 0) y *= LOG2E;   // fold softmax ln->log2 into Q
        vals[i] = f2bf(y);
    }

    if (oset < 2) {
        bf16x8 v0, v1;
#pragma unroll
        for (int i = 0; i < 8; i++) { v0[i] = (short)vals[i]; v1[i] = (short)vals[8 + i]; }
        if (oset == 0) {
            unsigned short* dst = qb + ((size_t)n * HW_ + p0 + p) * 64 + og * 16;
            *(bf16x8*)(dst)     = v0;
            *(bf16x8*)(dst + 8) = v1;
        } else {
            // K swizzled: chunks s = 2og, 2og+1 at slot s^(j&7), j = p0+p
            unsigned short* dst = kb + ((size_t)n * HW_ + p0 + p) * 64;
            *(bf16x8*)(dst + (((2 * og) ^ (p & 7)) * 8))     = v0;
            *(bf16x8*)(dst + (((2 * og + 1) ^ (p & 7)) * 8)) = v1;
        }
    } else {
        int c0 = obase - 128;
        int sp = p >> 3, ep = p & 7;
        unsigned short* vdst = vtb + (((size_t)n * NT_ + ptile) * CC) * 64;
#pragma unroll
        for (int i = 0; i < 16; i++) {
            int c = c0 + i;
            vdst[c * 64 + ((sp ^ (c & 7)) * 8) + ep] = vals[i];
        }
    }
}

// ---------------------------------------------------------------------------
// Kernel 3: flash attention, S^T form, 32x32x16 MFMA, no-max softmax.
//   r6 core + per-stream pacing barriers: the 36 blocks sharing a (chunk,n)
//   K/V stream sync every 4 j-tiles via a ticket counter -> tiles stay
//   L2-resident across all sharers (r2's 87%-hit regime) instead of each
//   block re-fetching from L3 (~2.1 TB/s service ceiling = r3-r6 plateau).
//   All 432 blocks co-resident (<=512 capacity) -> spin is deadlock-free;
//   counters only grow -> replay without memset degrades to no-op.
// ---------------------------------------------------------------------------
__global__ __launch_bounds__(256, 2) void attn_kernel(
    const unsigned short* __restrict__ qb, const unsigned short* __restrict__ kb,
    const unsigned short* __restrict__ vtb,
    float* __restrict__ o_part, float* __restrict__ l_part,
    int* __restrict__ sync_ctr) {
    const int qtb   = blockIdx.x;   // 36
    const int chunk = blockIdx.y;   // 6
    const int n     = blockIdx.z;   // 2
    const int t = threadIdx.x;
    const int w = t >> 6;
    const int lane = t & 63;
    const int l31 = lane & 31;
    const int h = lane >> 5;
    const int e7 = l31 & 7;

    // 3 buffers x (K 8 KB + V 16 KB) = 72 KB
    __shared__ __align__(16) unsigned short sbuf[3 * 12288];

    // Q B-frags: lane q = l31 (+qt*32 +w*64), d = dt*16 + h*8 + 0..7
    bf16x8 bq[2][4];
#pragma unroll
    for (int qt = 0; qt < 2; qt++) {
        const int row = qtb * 256 + w * 64 + qt * 32 + l31;
        const unsigned short* qp = qb + ((size_t)n * HW_ + row) * 64 + h * 8;
#pragma unroll
        for (int dt = 0; dt < 4; dt++)
            bq[qt][dt] = *(const bf16x8*)(qp + dt * 16);
    }
    // force Q completion before any DMA so the loop has no compiler-visible
    // vmem dependencies
    asm volatile("" : "+v"(bq[0][0]), "+v"(bq[0][1]), "+v"(bq[0][2]), "+v"(bq[0][3]),
                      "+v"(bq[1][0]), "+v"(bq[1][1]), "+v"(bq[1][2]), "+v"(bq[1][3]));

    f32x16 acc[4][2];
#pragma unroll
    for (int ct = 0; ct < 4; ct++)
#pragma unroll
        for (int qt = 0; qt < 2; qt++) acc[ct][qt] = (f32x16){};
    float l_s[2] = {0.f, 0.f};

    // LINEAR DMA sources (swizzle baked into kb/vtb by the conv):
    const int j0b = chunk * CHUNKJ;
    const int t0 = chunk * ITERS;
    const unsigned short* ks[2];
    const unsigned short* vs[4];
#pragma unroll
    for (int i = 0; i < 2; i++)
        ks[i] = kb + ((size_t)n * HW_ + j0b) * 64 + ((2 * w + i) * 64 + lane) * 8;
#pragma unroll
    for (int i = 0; i < 4; i++)
        vs[i] = vtb + (((size_t)n * NT_ + t0) * CC) * 64 + ((4 * w + i) * 64 + lane) * 8;

    // fragment-read byte offsets within a buffer
    int cho[4];
#pragma unroll
    for (int xx = 0; xx < 4; xx++) cho[xx] = ((xx * 2 + h) ^ e7) * 16;
    const int jr0 = l31 * 128, jr1 = (32 + l31) * 128;

    // prologue: DMA tiles 0 and 1 into buffers 0,1 (12/wave outstanding)
#pragma unroll
    for (int b = 0; b < 2; b++) {
        unsigned short* db = sbuf + b * 12288;
        cp16(ks[0] + b * 4096, db + (2 * w + 0) * 512);
        cp16(ks[1] + b * 4096, db + (2 * w + 1) * 512);
        cp16(vs[0] + b * 8192, db + 4096 + (4 * w + 0) * 512);
        cp16(vs[1] + b * 8192, db + 4096 + (4 * w + 1) * 512);
        cp16(vs[2] + b * 8192, db + 4096 + (4 * w + 2) * 512);
        cp16(vs[3] + b * 8192, db + 4096 + (4 * w + 3) * 512);
    }

    const int sid = n * NCH + chunk;   // stream id, 12 streams x 36 sharers

    int cur = 0;
    for (int tI = 0; tI < ITERS; ++tI) {
        // pacing barrier every 4 tiles (not at 0): resync the 36 sharers
        if ((tI & 3) == 0 && tI != 0) {
            if (t == 0) {
                int* ctr = sync_ctr + sid * 8 + ((tI >> 2) - 1);
                __hip_atomic_fetch_add(ctr, 1, __ATOMIC_RELAXED, __HIP_MEMORY_SCOPE_AGENT);
                while (__hip_atomic_load(ctr, __ATOMIC_RELAXED, __HIP_MEMORY_SCOPE_AGENT) < 36)
                    __builtin_amdgcn_s_sleep(2);
            }
            __syncthreads();   // also drains vmcnt (compiler) - fine, 5x only
        }

        // my 6 DMAs for the current tile done once <=6 remain outstanding;
        // barrier then guarantees ALL waves' DMAs for this buffer landed.
        asm volatile("s_waitcnt vmcnt(6)" ::: "memory");
        asm volatile("s_barrier" ::: "memory");

        {   // issue tile tI+2 into the buffer freed at this barrier
            int tt = tI + 2; if (tt >= ITERS) tt -= ITERS;   // wrap: hot re-read
            int nb = cur + 2; if (nb >= 3) nb -= 3;
            unsigned short* db = sbuf + nb * 12288;
            cp16(ks[0] + tt * 4096, db + (2 * w + 0) * 512);
            cp16(ks[1] + tt * 4096, db + (2 * w + 1) * 512);
            cp16(vs[0] + tt * 8192, db + 4096 + (4 * w + 0) * 512);
            cp16(vs[1] + tt * 8192, db + 4096 + (4 * w + 1) * 512);
            cp16(vs[2] + tt * 8192, db + 4096 + (4 * w + 2) * 512);
            cp16(vs[3] + tt * 8192, db + 4096 + (4 * w + 3) * 512);
        }

        const int bufB = cur * 24576;

        // K A-frags: j = jt*32 + l31, d-chunk = dt*2 + h (swizzled)
        u32x4 akr[2][4];
#pragma unroll
        for (int dt = 0; dt < 4; dt++) akr[0][dt] = ds_read16(bufB + jr0 + cho[dt]);
#pragma unroll
        for (int dt = 0; dt < 4; dt++) akr[1][dt] = ds_read16(bufB + jr1 + cho[dt]);
        lgkm0_tie8(akr[0][0], akr[0][1], akr[0][2], akr[0][3],
                   akr[1][0], akr[1][1], akr[1][2], akr[1][3]);
        bf16x8 ak[2][4];
#pragma unroll
        for (int jt = 0; jt < 2; jt++)
#pragma unroll
            for (int dt = 0; dt < 4; dt++) ak[jt][dt] = __builtin_bit_cast(bf16x8, akr[jt][dt]);

        // S^T, exp, sum, in-register transpose to P^T B-frags
        bf16x8 bp[2][4];
#pragma unroll
        for (int qt = 0; qt < 2; qt++) {
            f32x16 s0 = (f32x16){}, s1 = (f32x16){};
#pragma unroll
            for (int dt = 0; dt < 4; dt++) {
                s0 = __builtin_amdgcn_mfma_f32_32x32x16_bf16(ak[0][dt], bq[qt][dt], s0, 0, 0, 0);
                s1 = __builtin_amdgcn_mfma_f32_32x32x16_bf16(ak[1][dt], bq[qt][dt], s1, 0, 0, 0);
            }
            float sum = 0.f;
#pragma unroll
            for (int r = 0; r < 16; r++) {
                float p0 = exp2f(s0[r]); s0[r] = p0; sum += p0;
                float p1 = exp2f(s1[r]); s1[r] = p1; sum += p1;
            }
            sum += __shfl_xor(sum, 32);
            l_s[qt] += sum;

            // C/D (row=(r&3)+8(r>>2)+4h) -> B-frag (k=h*8+i): pack reg-quads,
            // swap halves via shfl_xor(32), select by h. (round-4 verified)
#pragma unroll
            for (int jt = 0; jt < 2; jt++) {
                const f32x16& s = (jt == 0) ? s0 : s1;
                unsigned int G[4][2], X[4][2];
#pragma unroll
                for (int g = 0; g < 4; g++) {
                    G[g][0] = (unsigned int)f2bf(s[4 * g + 0]) | ((unsigned int)f2bf(s[4 * g + 1]) << 16);
                    G[g][1] = (unsigned int)f2bf(s[4 * g + 2]) | ((unsigned int)f2bf(s[4 * g + 3]) << 16);
                    X[g][0] = __shfl_xor((int)G[g][0], 32);
                    X[g][1] = __shfl_xor((int)G[g][1], 32);
                }
                u32x4 fe = h ? (u32x4){X[1][0], X[1][1], G[1][0], G[1][1]}
                             : (u32x4){G[0][0], G[0][1], X[0][0], X[0][1]};
                u32x4 fo = h ? (u32x4){X[3][0], X[3][1], G[3][0], G[3][1]}
                             : (u32x4){G[2][0], G[2][1], X[2][0], X[2][1]};
                bp[qt][2 * jt]     = __builtin_bit_cast(bf16x8, fe);
                bp[qt][2 * jt + 1] = __builtin_bit_cast(bf16x8, fo);
            }
        }

        // O^T += V^T P^T
#pragma unroll
        for (int ct = 0; ct < 4; ct++) {
            const int vrow = 8192 + (ct * 32 + l31) * 128;
            u32x4 avr[4];
#pragma unroll
            for (int jc = 0; jc < 4; jc++) avr[jc] = ds_read16(bufB + vrow + cho[jc]);
            lgkm0_tie4(avr[0], avr[1], avr[2], avr[3]);
#pragma unroll
            for (int qt = 0; qt < 2; qt++)
#pragma unroll
                for (int jc = 0; jc < 4; jc++)
                    acc[ct][qt] = __builtin_amdgcn_mfma_f32_32x32x16_bf16(
                        __builtin_bit_cast(bf16x8, avr[jc]), bp[qt][jc], acc[ct][qt], 0, 0, 0);
        }

        cur = (cur == 2) ? 0 : cur + 1;
    }
    asm volatile("s_waitcnt vmcnt(0)" ::: "memory");   // drain wrap DMAs

    // partials: O^T[c][q]; c = ct*32 + (r&3)+8*(r>>2)+4h, q col = l31
    // nontemporal: o_part is stream-once data, keep it out of L2
    const size_t obase = ((size_t)(chunk * 2 + n) * CC) * HW_;
#pragma unroll
    for (int ct = 0; ct < 4; ct++)
#pragma unroll
        for (int qt = 0; qt < 2; qt++) {
            const int p = qtb * 256 + w * 64 + qt * 32 + l31;
#pragma unroll
            for (int r = 0; r < 16; r++) {
                const int c = ct * 32 + (r & 3) + 8 * (r >> 2) + 4 * h;
                __builtin_nontemporal_store(acc[ct][qt][r],
                                            &o_part[obase + (size_t)c * HW_ + p]);
            }
        }
    if (h == 0) {
#pragma unroll
        for (int qt = 0; qt < 2; qt++)
            __builtin_nontemporal_store(l_s[qt],
                &l_part[(size_t)(chunk * 2 + n) * HW_ + qtb * 256 + w * 64 + qt * 32 + l31]);
    }
}

// ---------------------------------------------------------------------------
// Kernel 4: combine NCH partials (plain sums - no max), write out[n][c][p].
// ---------------------------------------------------------------------------
__global__ __launch_bounds__(256) void combine_kernel(
    const float* __restrict__ o_part, const float* __restrict__ l_part,
    float* __restrict__ out) {
    int idx = blockIdx.x * 256 + threadIdx.x;   // < 2359296
    int p = idx % HW_;
    int nc = idx / HW_;          // n*128 + c
    int n = nc >> 7;
    float num = 0.f, den = 0.f;
#pragma unroll
    for (int ch = 0; ch < NCH; ch++) {
        num += __builtin_nontemporal_load(
            &o_part[((size_t)(ch * 2 + n) * CC + (nc & 127)) * HW_ + p]);
        den += __builtin_nontemporal_load(
            &l_part[(size_t)(ch * 2 + n) * HW_ + p]);
    }
    __builtin_nontemporal_store(num / den, &out[idx]);
}

// ---------------------------------------------------------------------------
// Workspace layout (bytes), ~66.6 MB total:
//   wt 0 (131072) | qb 131072 (2359296) | kb 2490368 (2359296, pre-swizzled)
//   vtb 4849664 (4718592, pre-swizzled+tiled) | o_part 9568256 (6*9437184)
//   l_part 66191360 (442368) | sync_ctr 66633728 (512)
// ---------------------------------------------------------------------------
extern "C" void kernel_launch(void* const* d_in, const int* in_sizes, int n_in,
                              void* d_out, int out_size, void* d_ws, size_t ws_size,
                              hipStream_t stream) {
    const float* x  = (const float*)d_in[0];
    const float* w1 = (const float*)d_in[1];
    const float* b1 = (const float*)d_in[2];
    const float* a1 = (const float*)d_in[3];
    const float* w2 = (const float*)d_in[4];
    const float* b2 = (const float*)d_in[5];
    const float* a2 = (const float*)d_in[6];
    const float* wa = (const float*)d_in[7];
    const float* ba = (const float*)d_in[8];
    const float* aa = (const float*)d_in[9];
    float* out = (float*)d_out;

    char* ws = (char*)d_ws;
    float*          wt     = (float*)(ws + 0);
    unsigned short* qb     = (unsigned short*)(ws + 131072);
    unsigned short* kb     = (unsigned short*)(ws + 2490368);
    unsigned short* vtb    = (unsigned short*)(ws + 4849664);
    float*          o_part = (float*)(ws + 9568256);
    float*          l_part = (float*)(ws + 66191360);
    int*            ctr    = (int*)(ws + CTR_OFF);

    hipMemsetAsync(ctr, 0, 512, stream);   // zero pacing counters every call
    hipLaunchKernelGGL(prep_w, dim3(128), dim3(256), 0, stream, w1, w2, wa, wt);
    hipLaunchKernelGGL(conv_kernel, dim3(144, 4, 2), dim3(256), 0, stream,
                       x, wt, b1, a1, b2, a2, ba, aa, qb, kb, vtb);
    hipLaunchKernelGGL(attn_kernel, dim3(36, NCH, 2), dim3(256), 0, stream,
                       qb, kb, vtb, o_part, l_part, ctr);
    hipLaunchKernelGGL(combine_kernel, dim3(2 * CC * HW_ / 256), dim3(256), 0, stream,
                       o_part, l_part, out);
}